// Round 3
// baseline (75.493 us; speedup 1.0000x reference)
//
#include <hip/hip_runtime.h>
#include <hip/hip_bf16.h>
#include <math.h>

#define N_NODES 2048
#define FIN 128
#define FOUT 64
#define BS 8
#define ALPHA 0.2f

typedef __attribute__((ext_vector_type(8))) short short8v;
typedef __attribute__((ext_vector_type(4))) float f32x4;

__device__ __forceinline__ unsigned int pack2bf(float a, float b) {
  __hip_bfloat162 t = __float22bfloat162_rn(make_float2(a, b));
  unsigned int r;
  __builtin_memcpy(&r, &t, 4);
  return r;
}

__device__ __forceinline__ float elu_f(float v) {
  return v > 0.f ? v : expm1f(v);
}

// ---------------- Kernel 1: fused h-compute + s1/s2 + bf16 fragment pack + mask pack
// Grid: 512 blocks (b = bx>>6, jt = bx&63 -> rows jt*32..jt*32+31 of batch b).
// 256 threads = 4 waves. Wave w: packs adj row bx*4+w; computes 8 h-rows; packs ct=w.
__global__ __launch_bounds__(256) void gat_prep(const float* __restrict__ x,
                                                const int* __restrict__ adj,
                                                const float* __restrict__ W,
                                                const float* __restrict__ a,
                                                short* __restrict__ hp,
                                                float* __restrict__ s1,
                                                float* __restrict__ s2,
                                                unsigned int* __restrict__ mask32) {
  const int bx = blockIdx.x;            // 0..511
  const int b = bx >> 6;                // batch
  const int jt = bx & 63;               // 32-row tile within batch
  const int t = threadIdx.x;
  const int w = t >> 6, lane = t & 63;

  __shared__ float h_lds[32][65];

  // ---- mask pack: adj row (bx*4 + w) -> 64 u32 bit-words (row shared by all batches)
  {
    const int row = bx * 4 + w;
    const int* ar = adj + (long long)row * N_NODES;
    for (int c = 0; c < 32; ++c) {
      const unsigned long long bal = __ballot(ar[c * 64 + lane] > 0);
      if (lane == 0) mask32[row * 64 + 2 * c] = (unsigned int)bal;
      if (lane == 1) mask32[row * 64 + 2 * c + 1] = (unsigned int)(bal >> 32);
    }
  }

  // ---- h rows (fp32) + s1/s2 projections; lane = output channel o
  const float a1v = a[lane], a2v = a[FOUT + lane];
  const int rbase = jt * 32;
  for (int rr = 0; rr < 8; ++rr) {
    const int rl_ = w * 8 + rr;
    const float* xr = x + ((long long)b * N_NODES + rbase + rl_) * FIN;
    float acc = 0.f;
    #pragma unroll 4
    for (int f = 0; f < FIN; f += 4) {
      const float4 xv = *reinterpret_cast<const float4*>(xr + f);
      acc = fmaf(xv.x, W[(f + 0) * FOUT + lane], acc);
      acc = fmaf(xv.y, W[(f + 1) * FOUT + lane], acc);
      acc = fmaf(xv.z, W[(f + 2) * FOUT + lane], acc);
      acc = fmaf(xv.w, W[(f + 3) * FOUT + lane], acc);
    }
    h_lds[rl_][lane] = acc;
    float r1 = acc * a1v, r2 = acc * a2v;
    #pragma unroll
    for (int off = 32; off > 0; off >>= 1) {
      r1 += __shfl_xor(r1, off);
      r2 += __shfl_xor(r2, off);
    }
    if (lane == 0) {
      s1[b * N_NODES + rbase + rl_] = r1;
      s2[b * N_NODES + rbase + rl_] = r2;
    }
  }
  __syncthreads();

  // ---- pack 32x64 fp32 tile -> bf16 B-fragment layout; wave w handles ct = w
  // element (j_local, o): lane = ((j>>3)&3)*16 + (o&15), e = j&7
  {
    const int kg = lane >> 4, cl = lane & 15;
    union { short8v v; unsigned int u[4]; } o;
    #pragma unroll
    for (int i = 0; i < 4; ++i)
      o.u[i] = pack2bf(h_lds[kg * 8 + 2 * i][w * 16 + cl],
                       h_lds[kg * 8 + 2 * i + 1][w * 16 + cl]);
    *reinterpret_cast<short8v*>(hp + (((long long)(b * 256 + jt * 4 + w)) * 64 + lane) * 8) = o.v;
  }
}

// ---------------- Kernel 2: fused p-gen (regs) + MFMA PV + row-sum MFMA
// Grid: (64 i-tiles, 8 b), 512 threads = 8 waves. Wave w: row-group rg2=w&1 (16 rows),
// j-stripe js=w>>1 (j-tiles js, js+4, ...). No barriers in main loop.
// A-frag: lane l holds p[row=l&15][k=(l>>4)*8+e]. C/D: col=l&15, row=(l>>4)*4+r.
__global__ __launch_bounds__(512) void gat_attn(const unsigned int* __restrict__ mask32,
                                                const short* __restrict__ hp,
                                                const float* __restrict__ s1g,
                                                const float* __restrict__ s2g,
                                                float* __restrict__ out) {
  const int b = blockIdx.y;
  const int i0 = blockIdx.x * 32;
  const int t = threadIdx.x;
  const int w = t >> 6, lane = t & 63;
  const int rg2 = w & 1, js = w >> 1;
  const int kg = lane >> 4, rl = lane & 15;

  __shared__ float red[8][16 * 64];   // 32 KB
  __shared__ float ps[8][16];

  const float s1v = s1g[b * N_NODES + i0 + rg2 * 16 + rl];
  const float* s2B = s2g + b * N_NODES;
  const unsigned int* mrow = mask32 + (i0 + rg2 * 16 + rl) * 64;
  const short8v* hpB = reinterpret_cast<const short8v*>(hp) + (long long)b * 16384;

  f32x4 acc0 = {0.f, 0.f, 0.f, 0.f};
  f32x4 acc1 = {0.f, 0.f, 0.f, 0.f};
  f32x4 acc2 = {0.f, 0.f, 0.f, 0.f};
  f32x4 acc3 = {0.f, 0.f, 0.f, 0.f};
  f32x4 accS = {0.f, 0.f, 0.f, 0.f};
  union { short8v v; unsigned int u[4]; } ones;
  #pragma unroll
  for (int i = 0; i < 4; ++i) ones.u[i] = 0x3F803F80u;

  for (int jt = js; jt < 64; jt += 4) {
    const short8v* hpt = hpB + jt * 256;
    const short8v b0 = hpt[0 * 64 + lane];
    const short8v b1 = hpt[1 * 64 + lane];
    const short8v b2 = hpt[2 * 64 + lane];
    const short8v b3 = hpt[3 * 64 + lane];
    const float4 sa = *reinterpret_cast<const float4*>(s2B + jt * 32 + kg * 8);
    const float4 sb = *reinterpret_cast<const float4*>(s2B + jt * 32 + kg * 8 + 4);
    const unsigned int m = mrow[jt] >> (kg * 8);
    const float s2e[8] = {sa.x, sa.y, sa.z, sa.w, sb.x, sb.y, sb.z, sb.w};
    float p[8];
    #pragma unroll
    for (int e = 0; e < 8; e++) {
      float sc = s1v + s2e[e];
      sc = fmaxf(sc, ALPHA * sc);                 // leaky-relu
      p[e] = ((m >> e) & 1u) ? __expf(sc) : 0.f;
    }
    union { short8v v; unsigned int u[4]; } af;
    #pragma unroll
    for (int i = 0; i < 4; ++i) af.u[i] = pack2bf(p[2 * i], p[2 * i + 1]);
    acc0 = __builtin_amdgcn_mfma_f32_16x16x32_bf16(af.v, b0, acc0, 0, 0, 0);
    acc1 = __builtin_amdgcn_mfma_f32_16x16x32_bf16(af.v, b1, acc1, 0, 0, 0);
    acc2 = __builtin_amdgcn_mfma_f32_16x16x32_bf16(af.v, b2, acc2, 0, 0, 0);
    acc3 = __builtin_amdgcn_mfma_f32_16x16x32_bf16(af.v, b3, acc3, 0, 0, 0);
    accS = __builtin_amdgcn_mfma_f32_16x16x32_bf16(af.v, ones.v, accS, 0, 0, 0);
  }

  #pragma unroll
  for (int r = 0; r < 4; r++) {
    red[w][(kg * 4 + r) * 64 + 0 * 16 + rl] = acc0[r];
    red[w][(kg * 4 + r) * 64 + 1 * 16 + rl] = acc1[r];
    red[w][(kg * 4 + r) * 64 + 2 * 16 + rl] = acc2[r];
    red[w][(kg * 4 + r) * 64 + 3 * 16 + rl] = acc3[r];
  }
  if (rl == 0) {
    #pragma unroll
    for (int r = 0; r < 4; r++) ps[w][kg * 4 + r] = accS[r];
  }
  __syncthreads();

  // epilogue: 512 threads x 4 outputs; sum the 4 j-stripe partials per row-group
  const int rowg = t >> 8;            // 0..1
  const int idx = t & 255;
  const int row16 = idx >> 4;         // 0..15
  const int c4 = (idx & 15) * 4;      // 0..60
  float den = 0.f;
  float vx = 0.f, vy = 0.f, vz = 0.f, vw = 0.f;
  #pragma unroll
  for (int s = 0; s < 4; ++s) {
    const int ww = s * 2 + rowg;
    den += ps[ww][row16];
    const float* rp = &red[ww][row16 * 64 + c4];
    vx += rp[0]; vy += rp[1]; vz += rp[2]; vw += rp[3];
  }
  const float inv = 1.0f / den;
  float4 ov;
  ov.x = elu_f(vx * inv); ov.y = elu_f(vy * inv);
  ov.z = elu_f(vz * inv); ov.w = elu_f(vw * inv);
  *reinterpret_cast<float4*>(
      out + ((long long)b * N_NODES + i0 + rowg * 16 + row16) * FOUT + c4) = ov;
}

extern "C" void kernel_launch(void* const* d_in, const int* in_sizes, int n_in,
                              void* d_out, int out_size, void* d_ws, size_t ws_size,
                              hipStream_t stream) {
  const float* x   = (const float*)d_in[0];
  const int*   adj = (const int*)d_in[1];
  const float* W   = (const float*)d_in[2];
  const float* a   = (const float*)d_in[3];
  float* out = (float*)d_out;

  short* hp = (short*)d_ws;                                        // BS*N*FOUT bf16 = 2 MB
  float* s1 = (float*)(hp + (long long)BS * N_NODES * FOUT);       // BS*N f32
  float* s2 = s1 + BS * N_NODES;                                   // BS*N f32
  unsigned int* mask32 = (unsigned int*)(s2 + BS * N_NODES);       // N*64 u32 = 512 KB

  gat_prep<<<BS * N_NODES / 32, 256, 0, stream>>>(x, adj, W, a, hp, s1, s2, mask32);
  gat_attn<<<dim3(N_NODES / 32, BS), 512, 0, stream>>>(mask32, hp, s1, s2, out);
}

// Round 4
// 68.637 us; speedup vs baseline: 1.0999x; 1.0999x over previous
//
#include <hip/hip_runtime.h>
#include <hip/hip_bf16.h>
#include <math.h>

#define N_NODES 2048
#define FIN 128
#define FOUT 64
#define BS 8
#define ALPHA 0.2f

typedef __attribute__((ext_vector_type(8))) short short8v;
typedef __attribute__((ext_vector_type(4))) float f32x4;

__device__ __forceinline__ unsigned int pack2bf(float a, float b) {
  __hip_bfloat162 t = __float22bfloat162_rn(make_float2(a, b));
  unsigned int r;
  __builtin_memcpy(&r, &t, 4);
  return r;
}

__device__ __forceinline__ float elu_f(float v) {
  return v > 0.f ? v : expm1f(v);
}

// ---------------- gat_h: h = x@W ; s1 = h@a1 ; s2 = h@a2 ----------------
// 4096 blocks x 4 waves; one (b,n) row per wave; lane = o. 4 accumulators for ILP.
__global__ __launch_bounds__(256) void gat_h(const float* __restrict__ x,
                                             const float* __restrict__ W,
                                             const float* __restrict__ a,
                                             float* __restrict__ h,
                                             float* __restrict__ s1,
                                             float* __restrict__ s2) {
  const int lane = threadIdx.x & 63;
  const int row = blockIdx.x * 4 + (threadIdx.x >> 6);   // 0 .. BS*N_NODES-1
  const float* xr = x + (long long)row * FIN;
  float acc0 = 0.f, acc1 = 0.f, acc2 = 0.f, acc3 = 0.f;
  #pragma unroll
  for (int f = 0; f < FIN; f += 16) {
    const float4 x0 = *reinterpret_cast<const float4*>(xr + f);
    const float4 x1 = *reinterpret_cast<const float4*>(xr + f + 4);
    const float4 x2 = *reinterpret_cast<const float4*>(xr + f + 8);
    const float4 x3 = *reinterpret_cast<const float4*>(xr + f + 12);
    acc0 = fmaf(x0.x, W[(f + 0) * FOUT + lane], acc0);
    acc1 = fmaf(x0.y, W[(f + 1) * FOUT + lane], acc1);
    acc2 = fmaf(x0.z, W[(f + 2) * FOUT + lane], acc2);
    acc3 = fmaf(x0.w, W[(f + 3) * FOUT + lane], acc3);
    acc0 = fmaf(x1.x, W[(f + 4) * FOUT + lane], acc0);
    acc1 = fmaf(x1.y, W[(f + 5) * FOUT + lane], acc1);
    acc2 = fmaf(x1.z, W[(f + 6) * FOUT + lane], acc2);
    acc3 = fmaf(x1.w, W[(f + 7) * FOUT + lane], acc3);
    acc0 = fmaf(x2.x, W[(f + 8) * FOUT + lane], acc0);
    acc1 = fmaf(x2.y, W[(f + 9) * FOUT + lane], acc1);
    acc2 = fmaf(x2.z, W[(f + 10) * FOUT + lane], acc2);
    acc3 = fmaf(x2.w, W[(f + 11) * FOUT + lane], acc3);
    acc0 = fmaf(x3.x, W[(f + 12) * FOUT + lane], acc0);
    acc1 = fmaf(x3.y, W[(f + 13) * FOUT + lane], acc1);
    acc2 = fmaf(x3.z, W[(f + 14) * FOUT + lane], acc2);
    acc3 = fmaf(x3.w, W[(f + 15) * FOUT + lane], acc3);
  }
  const float acc = (acc0 + acc1) + (acc2 + acc3);
  h[(long long)row * FOUT + lane] = acc;
  float r1 = acc * a[lane];
  float r2 = acc * a[FOUT + lane];
  #pragma unroll
  for (int off = 32; off > 0; off >>= 1) {
    r1 += __shfl_xor(r1, off);
    r2 += __shfl_xor(r2, off);
  }
  if (lane == 0) { s1[row] = r1; s2[row] = r2; }
}

// ------------- pack_h: h fp32 row-major -> bf16 B-fragment layout -------------
__global__ __launch_bounds__(256) void pack_h(const float* __restrict__ h,
                                              short* __restrict__ hp) {
  const int g = (blockIdx.x * 256 + threadIdx.x) >> 6;   // 0..2047
  const int lane = threadIdx.x & 63;
  const int b = g >> 8, rem = g & 255, jt = rem >> 2, ct = rem & 3;
  const int kg = lane >> 4, cl = lane & 15;
  const float* src = h + ((long long)b * N_NODES + jt * 32 + kg * 8) * FOUT + ct * 16 + cl;
  union { short8v v; unsigned int u[4]; } o;
  #pragma unroll
  for (int i = 0; i < 4; ++i)
    o.u[i] = pack2bf(src[(2 * i) * FOUT], src[(2 * i + 1) * FOUT]);
  *reinterpret_cast<short8v*>(hp + ((long long)g * 64 + lane) * 8) = o.v;
}

// ------------- pack_mask: adj int32 -> bitmask (uint32 per 32 j's) ------------
__global__ __launch_bounds__(256) void pack_mask(const int* __restrict__ adj,
                                                 unsigned int* __restrict__ mask32) {
  const int wid = (blockIdx.x * 256 + threadIdx.x) >> 6;  // 0..65535
  const int lane = threadIdx.x & 63;
  const int row = wid >> 5;                // 32 waves per row
  const int jb = (wid & 31) << 6;          // 64 j's per wave
  const int v = adj[(long long)row * N_NODES + jb + lane];
  const unsigned long long bal = __ballot(v > 0);
  if (lane == 0) mask32[row * 64 + (jb >> 5)] = (unsigned int)bal;
  if (lane == 1) mask32[row * 64 + (jb >> 5) + 1] = (unsigned int)(bal >> 32);
}

// ---------------- gat_attn: fused p-gen (regs) + MFMA PV + row-sum MFMA -------
// Grid (128 i-tiles of 16 rows, 8 b), 512 threads = 8 waves, wave w = j-stripe w
// (jt = w, w+8, ..., 56). No barriers in main loop.
// A-frag: lane l holds p[row=l&15][k=(l>>4)*8+e]. C/D: col(o)=l&15, row(i)=(l>>4)*4+r.
__global__ __launch_bounds__(512) void gat_attn(const unsigned int* __restrict__ mask32,
                                                const short* __restrict__ hp,
                                                const float* __restrict__ s1g,
                                                const float* __restrict__ s2g,
                                                float* __restrict__ out) {
  const int b = blockIdx.y;
  const int i0 = blockIdx.x * 16;
  const int t = threadIdx.x;
  const int w = t >> 6, lane = t & 63;
  const int kg = lane >> 4, rl = lane & 15;

  __shared__ float red[8][16 * 64];   // 32 KB
  __shared__ float ps[8][16];

  const float s1v = s1g[b * N_NODES + i0 + rl];
  const float* s2B = s2g + b * N_NODES;
  const unsigned int* mrow = mask32 + (i0 + rl) * 64;
  const short8v* hpB = reinterpret_cast<const short8v*>(hp) + (long long)b * 16384;

  f32x4 acc0 = {0.f, 0.f, 0.f, 0.f};
  f32x4 acc1 = {0.f, 0.f, 0.f, 0.f};
  f32x4 acc2 = {0.f, 0.f, 0.f, 0.f};
  f32x4 acc3 = {0.f, 0.f, 0.f, 0.f};
  f32x4 accS = {0.f, 0.f, 0.f, 0.f};
  union { short8v v; unsigned int u[4]; } ones;
  #pragma unroll
  for (int i = 0; i < 4; ++i) ones.u[i] = 0x3F803F80u;

  for (int jt = w; jt < 64; jt += 8) {
    const short8v* hpt = hpB + jt * 256;
    const short8v b0 = hpt[0 * 64 + lane];
    const short8v b1 = hpt[1 * 64 + lane];
    const short8v b2 = hpt[2 * 64 + lane];
    const short8v b3 = hpt[3 * 64 + lane];
    const float4 sa = *reinterpret_cast<const float4*>(s2B + jt * 32 + kg * 8);
    const float4 sb = *reinterpret_cast<const float4*>(s2B + jt * 32 + kg * 8 + 4);
    const unsigned int m = mrow[jt] >> (kg * 8);
    const float s2e[8] = {sa.x, sa.y, sa.z, sa.w, sb.x, sb.y, sb.z, sb.w};
    float p[8];
    #pragma unroll
    for (int e = 0; e < 8; e++) {
      float sc = s1v + s2e[e];
      sc = fmaxf(sc, ALPHA * sc);                 // leaky-relu
      p[e] = ((m >> e) & 1u) ? __expf(sc) : 0.f;
    }
    union { short8v v; unsigned int u[4]; } af;
    #pragma unroll
    for (int i = 0; i < 4; ++i) af.u[i] = pack2bf(p[2 * i], p[2 * i + 1]);
    acc0 = __builtin_amdgcn_mfma_f32_16x16x32_bf16(af.v, b0, acc0, 0, 0, 0);
    acc1 = __builtin_amdgcn_mfma_f32_16x16x32_bf16(af.v, b1, acc1, 0, 0, 0);
    acc2 = __builtin_amdgcn_mfma_f32_16x16x32_bf16(af.v, b2, acc2, 0, 0, 0);
    acc3 = __builtin_amdgcn_mfma_f32_16x16x32_bf16(af.v, b3, acc3, 0, 0, 0);
    accS = __builtin_amdgcn_mfma_f32_16x16x32_bf16(af.v, ones.v, accS, 0, 0, 0);
  }

  #pragma unroll
  for (int r = 0; r < 4; r++) {
    red[w][(kg * 4 + r) * 64 + 0 * 16 + rl] = acc0[r];
    red[w][(kg * 4 + r) * 64 + 1 * 16 + rl] = acc1[r];
    red[w][(kg * 4 + r) * 64 + 2 * 16 + rl] = acc2[r];
    red[w][(kg * 4 + r) * 64 + 3 * 16 + rl] = acc3[r];
  }
  if (rl == 0) {
    #pragma unroll
    for (int r = 0; r < 4; r++) ps[w][kg * 4 + r] = accS[r];
  }
  __syncthreads();

  // epilogue: 512 threads; thread -> (row = t>>5, cols c2, c2+1); sum 8 stripes
  const int row = t >> 5;
  const int c2 = (t & 31) * 2;
  float den = 0.f, v0 = 0.f, v1 = 0.f;
  #pragma unroll
  for (int s = 0; s < 8; ++s) {
    den += ps[s][row];
    const float* rp = &red[s][row * 64 + c2];
    v0 += rp[0]; v1 += rp[1];
  }
  const float inv = 1.0f / den;
  float2 ov;
  ov.x = elu_f(v0 * inv);
  ov.y = elu_f(v1 * inv);
  *reinterpret_cast<float2*>(
      out + ((long long)b * N_NODES + i0 + row) * FOUT + c2) = ov;
}

extern "C" void kernel_launch(void* const* d_in, const int* in_sizes, int n_in,
                              void* d_out, int out_size, void* d_ws, size_t ws_size,
                              hipStream_t stream) {
  const float* x   = (const float*)d_in[0];
  const int*   adj = (const int*)d_in[1];
  const float* W   = (const float*)d_in[2];
  const float* a   = (const float*)d_in[3];
  float* out = (float*)d_out;

  float* h  = (float*)d_ws;                                        // BS*N*FOUT f32 = 4 MB
  float* s1 = h + (long long)BS * N_NODES * FOUT;
  float* s2 = s1 + BS * N_NODES;
  short* hp = (short*)(s2 + BS * N_NODES);                         // BS*N*FOUT bf16 = 2 MB
  unsigned int* mask32 = (unsigned int*)(hp + (long long)BS * N_NODES * FOUT); // 512 KB

  gat_h<<<BS * N_NODES / 4, 256, 0, stream>>>(x, W, a, h, s1, s2);
  pack_mask<<<N_NODES * N_NODES / 64 / 4, 256, 0, stream>>>(adj, mask32);
  pack_h<<<BS * N_NODES * FOUT / 512 / 4, 256, 0, stream>>>(h, hp);
  gat_attn<<<dim3(N_NODES / 16, BS), 512, 0, stream>>>(mask32, hp, s1, s2, out);
}

// Round 5
// 54.706 us; speedup vs baseline: 1.3800x; 1.2547x over previous
//
#include <hip/hip_runtime.h>
#include <hip/hip_bf16.h>
#include <math.h>

#define N_NODES 2048
#define FIN 128
#define FOUT 64
#define BS 8
#define ALPHA 0.2f

typedef __attribute__((ext_vector_type(8))) short short8v;
typedef __attribute__((ext_vector_type(4))) float f32x4;

__device__ __forceinline__ unsigned int pack2bf(float a, float b) {
  __hip_bfloat162 t = __float22bfloat162_rn(make_float2(a, b));
  unsigned int r;
  __builtin_memcpy(&r, &t, 4);
  return r;
}

__device__ __forceinline__ float elu_f(float v) {
  return v > 0.f ? v : expm1f(v);
}

// ---------------- gat_prep: h(+LDS) + s1/s2 + bf16-fragment pack + mask pack --
// 512 blocks x 512 threads (8 waves). Block = (b = bx>>6, jt = bx&63): 32 rows.
// Wave w: computes local rows 4w..4w+3 with 4 independent FMA chains (W reused x4).
// Mask: wave w packs adj row bx*4 + (w>>1), j-half (w&1)*1024 (coalesced dword+ballot).
// Pack: waves 0..3 emit the 4 column-fragments of the 32x64 tile from LDS.
__global__ __launch_bounds__(512, 4) void gat_prep(const float* __restrict__ x,
                                                   const int* __restrict__ adj,
                                                   const float* __restrict__ W,
                                                   const float* __restrict__ a,
                                                   short* __restrict__ hp,
                                                   float* __restrict__ s1,
                                                   float* __restrict__ s2,
                                                   unsigned int* __restrict__ mask32) {
  const int bx = blockIdx.x;            // 0..511
  const int b = bx >> 6;                // batch
  const int jt = bx & 63;               // 32-row tile
  const int t = threadIdx.x;
  const int w = t >> 6, lane = t & 63;

  __shared__ float h_lds[32][65];

  // ---- h: 4 rows per wave, lane = output channel o ----
  const int r0 = jt * 32 + 4 * w;       // global node index of first row
  const float* xr = x + ((long long)b * N_NODES + r0) * FIN;
  float acc0 = 0.f, acc1 = 0.f, acc2 = 0.f, acc3 = 0.f;
  #pragma unroll 4
  for (int f = 0; f < FIN; f += 4) {
    const float4 x0 = *reinterpret_cast<const float4*>(xr + 0 * FIN + f);
    const float4 x1 = *reinterpret_cast<const float4*>(xr + 1 * FIN + f);
    const float4 x2 = *reinterpret_cast<const float4*>(xr + 2 * FIN + f);
    const float4 x3 = *reinterpret_cast<const float4*>(xr + 3 * FIN + f);
    const float w0 = W[(f + 0) * FOUT + lane];
    const float w1 = W[(f + 1) * FOUT + lane];
    const float w2 = W[(f + 2) * FOUT + lane];
    const float w3 = W[(f + 3) * FOUT + lane];
    acc0 = fmaf(x0.x, w0, acc0); acc0 = fmaf(x0.y, w1, acc0);
    acc0 = fmaf(x0.z, w2, acc0); acc0 = fmaf(x0.w, w3, acc0);
    acc1 = fmaf(x1.x, w0, acc1); acc1 = fmaf(x1.y, w1, acc1);
    acc1 = fmaf(x1.z, w2, acc1); acc1 = fmaf(x1.w, w3, acc1);
    acc2 = fmaf(x2.x, w0, acc2); acc2 = fmaf(x2.y, w1, acc2);
    acc2 = fmaf(x2.z, w2, acc2); acc2 = fmaf(x2.w, w3, acc2);
    acc3 = fmaf(x3.x, w0, acc3); acc3 = fmaf(x3.y, w1, acc3);
    acc3 = fmaf(x3.z, w2, acc3); acc3 = fmaf(x3.w, w3, acc3);
  }
  h_lds[4 * w + 0][lane] = acc0;
  h_lds[4 * w + 1][lane] = acc1;
  h_lds[4 * w + 2][lane] = acc2;
  h_lds[4 * w + 3][lane] = acc3;

  // ---- s1/s2: per-row 64-lane reductions ----
  {
    const float a1v = a[lane], a2v = a[FOUT + lane];
    float p0 = acc0 * a1v, p1 = acc1 * a1v, p2 = acc2 * a1v, p3 = acc3 * a1v;
    float q0 = acc0 * a2v, q1 = acc1 * a2v, q2 = acc2 * a2v, q3 = acc3 * a2v;
    #pragma unroll
    for (int off = 32; off > 0; off >>= 1) {
      p0 += __shfl_xor(p0, off); p1 += __shfl_xor(p1, off);
      p2 += __shfl_xor(p2, off); p3 += __shfl_xor(p3, off);
      q0 += __shfl_xor(q0, off); q1 += __shfl_xor(q1, off);
      q2 += __shfl_xor(q2, off); q3 += __shfl_xor(q3, off);
    }
    if (lane == 0) {
      const long long base = (long long)b * N_NODES + r0;
      s1[base + 0] = p0; s1[base + 1] = p1; s1[base + 2] = p2; s1[base + 3] = p3;
      s2[base + 0] = q0; s2[base + 1] = q1; s2[base + 2] = q2; s2[base + 3] = q3;
    }
  }

  // ---- mask pack: adj row bx*4 + (w>>1), half (w&1) ----
  {
    const int mrow = bx * 4 + (w >> 1);
    const int joff = (w & 1) * 1024;
    const int* ar = adj + (long long)mrow * N_NODES + joff;
    unsigned int* mw = mask32 + mrow * 64 + (joff >> 5);
    #pragma unroll 4
    for (int c = 0; c < 16; ++c) {
      const unsigned long long bal = __ballot(ar[c * 64 + lane] > 0);
      if (lane == 0) mw[2 * c] = (unsigned int)bal;
      if (lane == 1) mw[2 * c + 1] = (unsigned int)(bal >> 32);
    }
  }

  __syncthreads();

  // ---- pack 32x64 tile -> bf16 B-fragments; wave w<4 handles ct=w ----
  if (w < 4) {
    const int kg = lane >> 4, cl = lane & 15;
    union { short8v v; unsigned int u[4]; } o;
    #pragma unroll
    for (int i = 0; i < 4; ++i)
      o.u[i] = pack2bf(h_lds[kg * 8 + 2 * i][w * 16 + cl],
                       h_lds[kg * 8 + 2 * i + 1][w * 16 + cl]);
    *reinterpret_cast<short8v*>(hp + (((long long)(b * 256 + jt * 4 + w)) * 64 + lane) * 8) = o.v;
  }
}

// ---------------- gat_attn: fused p-gen (regs) + MFMA PV + row-sum MFMA -------
// Grid (128 i-tiles of 16 rows, 8 b), 512 threads = 8 waves, wave w = j-stripe w.
// A-frag: lane l holds p[row=l&15][k=(l>>4)*8+e]. C/D: col(o)=l&15, row(i)=(l>>4)*4+r.
__global__ __launch_bounds__(512) void gat_attn(const unsigned int* __restrict__ mask32,
                                                const short* __restrict__ hp,
                                                const float* __restrict__ s1g,
                                                const float* __restrict__ s2g,
                                                float* __restrict__ out) {
  const int b = blockIdx.y;
  const int i0 = blockIdx.x * 16;
  const int t = threadIdx.x;
  const int w = t >> 6, lane = t & 63;
  const int kg = lane >> 4, rl = lane & 15;

  __shared__ float red[8][16 * 64];   // 32 KB
  __shared__ float ps[8][16];

  const float s1v = s1g[b * N_NODES + i0 + rl];
  const float* s2B = s2g + b * N_NODES;
  const unsigned int* mrow = mask32 + (i0 + rl) * 64;
  const short8v* hpB = reinterpret_cast<const short8v*>(hp) + (long long)b * 16384;

  f32x4 acc0 = {0.f, 0.f, 0.f, 0.f};
  f32x4 acc1 = {0.f, 0.f, 0.f, 0.f};
  f32x4 acc2 = {0.f, 0.f, 0.f, 0.f};
  f32x4 acc3 = {0.f, 0.f, 0.f, 0.f};
  f32x4 accS = {0.f, 0.f, 0.f, 0.f};
  union { short8v v; unsigned int u[4]; } ones;
  #pragma unroll
  for (int i = 0; i < 4; ++i) ones.u[i] = 0x3F803F80u;

  for (int jt = w; jt < 64; jt += 8) {
    const short8v* hpt = hpB + jt * 256;
    const short8v b0 = hpt[0 * 64 + lane];
    const short8v b1 = hpt[1 * 64 + lane];
    const short8v b2 = hpt[2 * 64 + lane];
    const short8v b3 = hpt[3 * 64 + lane];
    const float4 sa = *reinterpret_cast<const float4*>(s2B + jt * 32 + kg * 8);
    const float4 sb = *reinterpret_cast<const float4*>(s2B + jt * 32 + kg * 8 + 4);
    const unsigned int m = mrow[jt] >> (kg * 8);
    const float s2e[8] = {sa.x, sa.y, sa.z, sa.w, sb.x, sb.y, sb.z, sb.w};
    float p[8];
    #pragma unroll
    for (int e = 0; e < 8; e++) {
      float sc = s1v + s2e[e];
      sc = fmaxf(sc, ALPHA * sc);                 // leaky-relu
      p[e] = ((m >> e) & 1u) ? __expf(sc) : 0.f;
    }
    union { short8v v; unsigned int u[4]; } af;
    #pragma unroll
    for (int i = 0; i < 4; ++i) af.u[i] = pack2bf(p[2 * i], p[2 * i + 1]);
    acc0 = __builtin_amdgcn_mfma_f32_16x16x32_bf16(af.v, b0, acc0, 0, 0, 0);
    acc1 = __builtin_amdgcn_mfma_f32_16x16x32_bf16(af.v, b1, acc1, 0, 0, 0);
    acc2 = __builtin_amdgcn_mfma_f32_16x16x32_bf16(af.v, b2, acc2, 0, 0, 0);
    acc3 = __builtin_amdgcn_mfma_f32_16x16x32_bf16(af.v, b3, acc3, 0, 0, 0);
    accS = __builtin_amdgcn_mfma_f32_16x16x32_bf16(af.v, ones.v, accS, 0, 0, 0);
  }

  #pragma unroll
  for (int r = 0; r < 4; r++) {
    red[w][(kg * 4 + r) * 64 + 0 * 16 + rl] = acc0[r];
    red[w][(kg * 4 + r) * 64 + 1 * 16 + rl] = acc1[r];
    red[w][(kg * 4 + r) * 64 + 2 * 16 + rl] = acc2[r];
    red[w][(kg * 4 + r) * 64 + 3 * 16 + rl] = acc3[r];
  }
  if (rl == 0) {
    #pragma unroll
    for (int r = 0; r < 4; r++) ps[w][kg * 4 + r] = accS[r];
  }
  __syncthreads();

  // epilogue: 512 threads; thread -> (row = t>>5, cols c2, c2+1); sum 8 stripes
  const int row = t >> 5;
  const int c2 = (t & 31) * 2;
  float den = 0.f, v0 = 0.f, v1 = 0.f;
  #pragma unroll
  for (int s = 0; s < 8; ++s) {
    den += ps[s][row];
    const float* rp = &red[s][row * 64 + c2];
    v0 += rp[0]; v1 += rp[1];
  }
  const float inv = 1.0f / den;
  float2 ov;
  ov.x = elu_f(v0 * inv);
  ov.y = elu_f(v1 * inv);
  *reinterpret_cast<float2*>(
      out + ((long long)b * N_NODES + i0 + row) * FOUT + c2) = ov;
}

extern "C" void kernel_launch(void* const* d_in, const int* in_sizes, int n_in,
                              void* d_out, int out_size, void* d_ws, size_t ws_size,
                              hipStream_t stream) {
  const float* x   = (const float*)d_in[0];
  const int*   adj = (const int*)d_in[1];
  const float* W   = (const float*)d_in[2];
  const float* a   = (const float*)d_in[3];
  float* out = (float*)d_out;

  short* hp = (short*)d_ws;                                        // BS*N*FOUT bf16 = 2 MB
  float* s1 = (float*)(hp + (long long)BS * N_NODES * FOUT);       // BS*N f32
  float* s2 = s1 + BS * N_NODES;                                   // BS*N f32
  unsigned int* mask32 = (unsigned int*)(s2 + BS * N_NODES);       // N*64 u32 = 512 KB

  gat_prep<<<512, 512, 0, stream>>>(x, adj, W, a, hp, s1, s2, mask32);
  gat_attn<<<dim3(N_NODES / 16, BS), 512, 0, stream>>>(mask32, hp, s1, s2, out);
}